// Round 3
// baseline (810.243 us; speedup 1.0000x reference)
//
#include <hip/hip_runtime.h>

// Problem constants (fixed by reference)
#define NN   50000
#define DD   16
#define FFE  256
#define HH   8
#define DHH  32
#define RR   20
#define HOPN 10

typedef unsigned short u16;
typedef unsigned int   u32;
typedef __attribute__((ext_vector_type(8))) short  short8;   // 8 bf16 = 4 VGPRs
typedef __attribute__((ext_vector_type(4))) float  floatx4;
typedef __attribute__((ext_vector_type(4))) double doublex4; // f64 MFMA acc

__device__ __forceinline__ float b2f(u16 u){ return __uint_as_float(((u32)u)<<16); }
__device__ __forceinline__ u16 f2b(float f){
  u32 x = __float_as_uint(f);
  u32 r = (x + 0x7fffu + ((x>>16)&1u)) >> 16;   // RNE
  return (u16)r;
}

// Async global->LDS DMA, 16B per lane. Dest must be wave-uniform base
// (HW adds lane*16); source is per-lane.
__device__ __forceinline__ void glds16(const u16* g, u16* l) {
  __builtin_amdgcn_global_load_lds(
      (const __attribute__((address_space(1))) void*)g,
      (__attribute__((address_space(3))) void*)l, 16, 0, 0);
}

// ---------------------------------------------------------------------------
// castw: one-off cast+transpose of value-path weights to bf16 [N][K] layout.
// ---------------------------------------------------------------------------
__global__ __launch_bounds__(256) void castw_kernel(
    const float* __restrict__ We, const float* __restrict__ W1,
    const float* __restrict__ W2,
    u16* __restrict__ Wet, u16* __restrict__ W1t, u16* __restrict__ W2t)
{
  int tid = blockIdx.x*256 + threadIdx.x;
  if (tid < 256*256) {                       // W_ent [256][256] -> Wet[n][k]
    int k = tid >> 8, n = tid & 255;
    Wet[n*256 + k] = f2b(We[tid]);
  } else if (tid < 256*256 + 256*1024) {     // W1 [256][1024] -> W1t[n][k]
    int s = tid - 65536;
    int k = s >> 10, n = s & 1023;
    W1t[n*256 + k] = f2b(W1[s]);
  } else if (tid < 589824) {                 // W2 [1024][256] -> W2t[n][k]
    int s = tid - 327680;
    int k = s >> 8, n = s & 255;
    W2t[n*1024 + k] = f2b(W2[s]);
  }
}

// ---------------------------------------------------------------------------
// prep: blocks 0..19 -> LN(rel_feat[r]) @ W_rel -> er[r,h]  (fp64, selection)
//       block 20     -> fold attn into Wcomb[256][16]: cols 0..7 = head,
//                       cols 8..15 = tail (mfma_f64_16x16x4 B layout).
// ---------------------------------------------------------------------------
__global__ __launch_bounds__(256) void prep_kernel(
    const float* __restrict__ rel_feat,
    const float* __restrict__ W_head, const float* __restrict__ W_tail,
    const float* __restrict__ W_rel,
    const float* __restrict__ attn_h, const float* __restrict__ attn_t,
    const float* __restrict__ attn_r,
    const float* __restrict__ lng, const float* __restrict__ lnb,
    double* __restrict__ Wcomb, double* __restrict__ er)
{
  int t = threadIdx.x;
  if (blockIdx.x == RR) {
    for (int h = 0; h < HH; h++) {
      double sh = 0.0, st = 0.0;
      #pragma unroll
      for (int c = 0; c < DHH; c++) {
        int j = h*DHH + c;
        sh += (double)W_head[t*FFE + j] * (double)attn_h[j];
        st += (double)W_tail[t*FFE + j] * (double)attn_t[j];
      }
      Wcomb[t*16 + h]     = sh;   // k = t, n = h      (head side)
      Wcomb[t*16 + 8 + h] = st;   // k = t, n = 8 + h  (tail side)
    }
    return;
  }
  int r = blockIdx.x;
  __shared__ double red[8];
  __shared__ double rln[256];
  double v = (double)rel_feat[r*FFE + t];
  double s = v, q = v*v;
  #pragma unroll
  for (int o = 32; o; o >>= 1) { s += __shfl_xor(s, o, 64); q += __shfl_xor(q, o, 64); }
  if ((t & 63) == 0) { red[t>>6] = s; red[4 + (t>>6)] = q; }
  __syncthreads();
  double stot = red[0]+red[1]+red[2]+red[3];
  double qtot = red[4]+red[5]+red[6]+red[7];
  double mean = stot * (1.0/256.0);
  double var  = qtot * (1.0/256.0) - mean*mean;
  double rstd = 1.0 / sqrt(var + 1e-5);
  rln[t] = (v - mean) * rstd * (double)lng[t] + (double)lnb[t];
  __syncthreads();
  double acc = 0.0;
  for (int k = 0; k < 256; k++) acc += rln[k] * (double)W_rel[k*FFE + t];
  double p = acc * (double)attn_r[t];
  #pragma unroll
  for (int o = 16; o; o >>= 1) p += __shfl_down(p, o, 32);
  if ((t & 31) == 0) er[r*HH + (t>>5)] = p;
}

// ---------------------------------------------------------------------------
// logits: per 16-node tile. LN(ent) in fp64 -> xb (bf16, value path) and
//         eh/et via mfma_f64_16x16x4 (16x16x256 fp64 GEMM per block,
//         K split across the 4 waves, partials reduced via LDS).
// ---------------------------------------------------------------------------
__global__ __launch_bounds__(256) void logits_kernel(
    const float* __restrict__ ent,
    const float* __restrict__ lng, const float* __restrict__ lnb,
    const double* __restrict__ Wcomb,
    u16* __restrict__ xb, double* __restrict__ eh, double* __restrict__ et)
{
  __shared__ double xs[16][257];      // 32.9 KB; also reused for partials
  int tid = threadIdx.x;
  int i0 = blockIdx.x * 16;
  int wave = tid >> 6, lane = tid & 63;
  for (int m = wave; m < 16; m += 4) {
    int row = i0 + m;
    float4 u = *(const float4*)&ent[row*FFE + lane*4];
    double v0 = u.x, v1 = u.y, v2 = u.z, v3 = u.w;
    double s = v0+v1+v2+v3;
    double q = v0*v0 + v1*v1 + v2*v2 + v3*v3;
    #pragma unroll
    for (int o = 32; o; o >>= 1) { s += __shfl_xor(s, o, 64); q += __shfl_xor(q, o, 64); }
    double mean = s * (1.0/256.0);
    double var  = q * (1.0/256.0) - mean*mean;
    double rstd = 1.0 / sqrt(var + 1e-5);
    float4 ug = *(const float4*)&lng[lane*4];
    float4 ub = *(const float4*)&lnb[lane*4];
    double y0 = (v0-mean)*rstd*(double)ug.x + (double)ub.x;
    double y1 = (v1-mean)*rstd*(double)ug.y + (double)ub.y;
    double y2 = (v2-mean)*rstd*(double)ug.z + (double)ub.z;
    double y3 = (v3-mean)*rstd*(double)ug.w + (double)ub.w;
    int c = lane*4;
    xs[m][c] = y0; xs[m][c+1] = y1; xs[m][c+2] = y2; xs[m][c+3] = y3;
    ushort4 o4;
    o4.x = f2b((float)y0); o4.y = f2b((float)y1);
    o4.z = f2b((float)y2); o4.w = f2b((float)y3);
    *(ushort4*)&xb[row*FFE + c] = o4;
  }
  __syncthreads();
  // phase 2: wave w owns K slice [w*64, w*64+64). mfma_f64_16x16x4:
  //   A[m][k]: lane = 16*(k&3) + m ; B[k][n]: lane = 16*(k&3) + n
  //   D[m][n]: col = lane&15, row = (lane>>4)*4 + reg
  int nl = lane & 15, kg = lane >> 4;
  doublex4 c4 = {0.0, 0.0, 0.0, 0.0};
  #pragma unroll
  for (int kk = 0; kk < 16; kk++) {
    int k = wave*64 + kk*4 + kg;
    double a = xs[nl][k];
    double b = Wcomb[k*16 + nl];
    c4 = __builtin_amdgcn_mfma_f64_16x16x4f64(a, b, c4, 0, 0, 0);
  }
  __syncthreads();                    // all xs reads done -> alias as partials
  double* sp = &xs[0][0];             // part[w][m][n] = sp[w*256 + m*16 + n]
  #pragma unroll
  for (int i = 0; i < 4; i++)
    sp[wave*256 + (kg*4 + i)*16 + nl] = c4[i];
  __syncthreads();
  int m = tid >> 4, n = tid & 15;     // one (row, output) per thread
  double v = sp[tid] + sp[256 + tid] + sp[512 + tid] + sp[768 + tid];
  if (n < 8) eh[(i0+m)*HH + n] = v;
  else       et[(i0+m)*HH + (n-8)] = v;
}

// ---------------------------------------------------------------------------
// gemm: C[M,N] = A[M,K]bf16 @ B[N,K]bf16 (B pre-transposed), MFMA 16x16x32.
// 2-phase double-buffered pipeline (T3-minimal): STAGE(buf^1, t+1) issued
// BEFORE compute(buf[t&1]); one __syncthreads per K-step (compiler emits
// vmcnt(0)+lgkmcnt(0) before s_barrier = exactly the required wait). The
// prefetch's HBM latency hides under ds_read + 32 MFMA instead of being
// serially drained. 128x128 tile, BK=64, 4 waves (2x2, 64x64 out each).
// LDS 64 KB (2 blocks/CU = today's measured residency; no occupancy loss).
// XOR swizzle (granule ^= row&7) on pre-swizzled global source + ds_read
// side kept bit-identical to round 2 (measured 0 bank conflicts).
// EPI 0: bf16 store. EPI 1: relu(v+bias) bf16. EPI 2: v+bias+feat+ent fp32.
// ---------------------------------------------------------------------------
template<int EPI>
__global__ __launch_bounds__(256) void gemm_kernel(
    const u16* __restrict__ A, const u16* __restrict__ B,
    const float* __restrict__ bias,
    const u16* __restrict__ feat, const float* __restrict__ ent,
    u16* __restrict__ Obf, float* __restrict__ Of,
    int M, int N, int K)
{
  __shared__ u16 As[2][128*64];   // 32 KB
  __shared__ u16 Bs[2][128*64];   // 32 KB
  int t = threadIdx.x;
  int i0 = blockIdx.x * 128;
  int n0 = blockIdx.y * 128;
  int w = t >> 6, l = t & 63;
  int wr = w >> 1, wc = w & 1;            // wave -> 64x64 quadrant

  // Staging: wave w stages tile rows [w*32, w*32+32) in 4 chunks of 8 rows.
  // Chunk j: LDS base (w*4+j)*512 u16 (wave-uniform). Lane l covers
  // row = w*32 + j*8 + (l>>3), swizzled source col ((l&7)^(l>>3))*8.
  int lrow = l >> 3;
  int scol = ((l & 7) ^ lrow) * 8;        // pre-swizzled global k-offset (u16)
  const u16* Ab[4]; const u16* Bb[4];
  #pragma unroll
  for (int j = 0; j < 4; j++) {
    int ra = w*32 + j*8 + lrow;           // tile row this lane sources
    int ga = min(i0 + ra, M-1);           // clamp M boundary (stores predicated)
    Ab[j] = &A[(size_t)ga*K + scol];
    Bb[j] = &B[(size_t)(n0 + ra)*K + scol];   // N always multiple of 128
  }

  // Fragment reads: row = q*64 + f*16 + ln; row&7 == ln&7.
  // u16 col = (ks*32 + (l>>4)*8) ^ ((ln&7)<<3).
  int ln = l & 15, q = l >> 4;
  int colk0 = (q*8) ^ ((ln & 7) << 3);
  int colk1 = colk0 ^ 32;

  floatx4 acc[4][4];
  #pragma unroll
  for (int mt = 0; mt < 4; mt++)
    #pragma unroll
    for (int nt = 0; nt < 4; nt++) acc[mt][nt] = (floatx4){0.f,0.f,0.f,0.f};

#define STAGE(buf, kk) do {                                   \
    _Pragma("unroll")                                         \
    for (int j = 0; j < 4; j++) {                             \
      glds16(Ab[j] + (kk), &As[buf][(w*4+j)*512]);            \
      glds16(Bb[j] + (kk), &Bs[buf][(w*4+j)*512]);            \
    } } while (0)

  STAGE(0, 0);
  __syncthreads();                        // prologue tile ready
  int nt_ = K >> 6;
  for (int ts = 0; ts < nt_; ts++) {
    int cb = ts & 1;
    if (ts + 1 < nt_) STAGE(cb ^ 1, (ts + 1) << 6);   // prefetch next tile
    #pragma unroll
    for (int ks = 0; ks < 2; ks++) {
      int ck = ks ? colk1 : colk0;
      short8 bfr[4], afr[4];
      #pragma unroll
      for (int nt = 0; nt < 4; nt++)
        bfr[nt] = *(const short8*)&Bs[cb][(wc*64 + nt*16 + ln)*64 + ck];
      #pragma unroll
      for (int mt = 0; mt < 4; mt++)
        afr[mt] = *(const short8*)&As[cb][(wr*64 + mt*16 + ln)*64 + ck];
      #pragma unroll
      for (int mt = 0; mt < 4; mt++)
        #pragma unroll
        for (int nt = 0; nt < 4; nt++)
          acc[mt][nt] = __builtin_amdgcn_mfma_f32_16x16x32_bf16(afr[mt], bfr[nt], acc[mt][nt], 0, 0, 0);
    }
    __syncthreads();   // drains prefetch vmcnt + joins readers before overwrite
  }
#undef STAGE

  int lr = q * 4;               // C/D layout: col=lane&15, row=(lane>>4)*4+reg
  #pragma unroll
  for (int mt = 0; mt < 4; mt++) {
    #pragma unroll
    for (int nt = 0; nt < 4; nt++) {
      int col = n0 + wc*64 + nt*16 + ln;
      #pragma unroll
      for (int r = 0; r < 4; r++) {
        int row = i0 + wr*64 + mt*16 + lr + r;
        if (row < M) {
          float v = acc[mt][nt][r];
          if (EPI == 0) {
            Obf[(size_t)row*N + col] = f2b(v);
          } else if (EPI == 1) {
            v += bias[col];
            Obf[(size_t)row*N + col] = f2b(v > 0.f ? v : 0.f);
          } else {
            v += bias[col] + b2f(feat[(size_t)row*FFE + col]) + ent[(size_t)row*FFE + col];
            Of[(size_t)row*N + col] = v;
          }
        }
      }
    }
  }
}

// ---------------------------------------------------------------------------
// edge: per (i,h): e_d = leaky(eh[src]+et+er[rid]) in fp64; top-5 (+1 tie slot);
//       weights = exp(e-max)/sum_top5, prescaled by (1-ALPHA)=0.9.
// ---------------------------------------------------------------------------
__global__ __launch_bounds__(256) void edge_kernel(
    const int* __restrict__ src, const int* __restrict__ rid,
    const double* __restrict__ eh, const double* __restrict__ et,
    const double* __restrict__ er,
    int* __restrict__ idx6, float* __restrict__ w6)
{
  int tid = blockIdx.x*256 + threadIdx.x;
  if (tid >= NN*HH) return;
  int i = tid >> 3, h = tid & 7;
  double bet = et[tid];
  double e[16]; int sj[16];
  #pragma unroll
  for (int d = 0; d < 16; d++) {
    int s = src[i*DD + d];
    int rv = rid[i*DD + d];
    sj[d] = s;
    double v = eh[s*HH + h] + bet + er[rv*HH + h];
    e[d] = (v > 0.0) ? v : 0.2 * v;
  }
  u32 mask = 0; double vs[5]; int js[5];
  #pragma unroll
  for (int k = 0; k < 5; k++) {
    double best = -1e300; int bj = 0, bd = 0;
    #pragma unroll
    for (int d = 0; d < 16; d++) {
      bool c = (((mask>>d)&1u) == 0u) && (e[d] > best);
      if (c) { best = e[d]; bj = sj[d]; bd = d; }
    }
    mask |= (1u << bd); vs[k] = best; js[k] = bj;
  }
  double kth = vs[4];
  int j6 = 0; bool f6 = false;
  #pragma unroll
  for (int d = 0; d < 16; d++) {
    if ((((mask>>d)&1u) == 0u) && (e[d] == kth) && !f6) { j6 = sj[d]; f6 = true; }
  }
  float m0 = (float)vs[0];
  float ex[5], ssum = 0.f;
  #pragma unroll
  for (int k = 0; k < 5; k++) { ex[k] = __expf((float)vs[k] - m0); ssum += ex[k]; }
  float inv = 0.9f / ssum;
  long base = (long)tid * 6;
  #pragma unroll
  for (int k = 0; k < 5; k++) { idx6[base+k] = js[k]; w6[base+k] = ex[k]*inv; }
  idx6[base+5] = j6; w6[base+5] = f6 ? ex[4]*inv : 0.f;
}

// ---------------------------------------------------------------------------
// diff: one hop. feat_new = 0.9*sum_k w*feat_old[idx] + 0.1*fe. Block = node.
// 50000 blocks => massive memory-level parallelism. Tie slot (w==0) skipped.
// ---------------------------------------------------------------------------
__global__ __launch_bounds__(256) void diff_kernel(
    const u16* __restrict__ fold, const u16* __restrict__ fe,
    const int* __restrict__ idx6, const float* __restrict__ w6,
    u16* __restrict__ fnew)
{
  int i = blockIdx.x, tid = threadIdx.x;
  int h = tid >> 5, c = tid & 31;
  long eb = ((long)i*HH + h) * 6;
  float acc = 0.1f * b2f(fe[i*FFE + tid]);
  #pragma unroll
  for (int k = 0; k < 5; k++) {
    int j = idx6[eb + k];
    float w = w6[eb + k];
    acc += w * b2f(fold[(size_t)j*FFE + h*DHH + c]);
  }
  float w5 = w6[eb + 5];
  if (w5 != 0.f) {
    int j = idx6[eb + 5];
    acc += w5 * b2f(fold[(size_t)j*FFE + h*DHH + c]);
  }
  fnew[i*FFE + tid] = f2b(acc);
}

// ---------------------------------------------------------------------------
// ln_ff: y = bf16( LN(feat+ent) ).  One wave per row, lane holds 4 elems.
// ---------------------------------------------------------------------------
__global__ __launch_bounds__(256) void ln_ff_kernel(
    const u16* __restrict__ feat, const float* __restrict__ ent,
    const float* __restrict__ g, const float* __restrict__ b,
    u16* __restrict__ y)
{
  int w = threadIdx.x >> 6, l = threadIdx.x & 63;
  int row = blockIdx.x*4 + w;
  float4 e4 = *(const float4*)&ent[row*FFE + l*4];
  ushort4 fv = *(const ushort4*)&feat[row*FFE + l*4];
  float v0 = b2f(fv.x)+e4.x, v1 = b2f(fv.y)+e4.y;
  float v2 = b2f(fv.z)+e4.z, v3 = b2f(fv.w)+e4.w;
  float s = v0+v1+v2+v3;
  float q = v0*v0 + v1*v1 + v2*v2 + v3*v3;
  #pragma unroll
  for (int o = 32; o; o >>= 1) { s += __shfl_xor(s, o, 64); q += __shfl_xor(q, o, 64); }
  float mean = s * (1.f/256.f);
  float var  = q * (1.f/256.f) - mean*mean;
  float rstd = rsqrtf(var + 1e-5f);
  float4 g4 = *(const float4*)&g[l*4];
  float4 b4 = *(const float4*)&b[l*4];
  ushort4 o4;
  o4.x = f2b((v0-mean)*rstd*g4.x + b4.x);
  o4.y = f2b((v1-mean)*rstd*g4.y + b4.y);
  o4.z = f2b((v2-mean)*rstd*g4.z + b4.z);
  o4.w = f2b((v3-mean)*rstd*g4.w + b4.w);
  *(ushort4*)&y[row*FFE + l*4] = o4;
}

// ---------------------------------------------------------------------------
extern "C" void kernel_launch(void* const* d_in, const int* in_sizes, int n_in,
                              void* d_out, int out_size, void* d_ws, size_t ws_size,
                              hipStream_t stream)
{
  const float* ent      = (const float*)d_in[0];
  const float* rel      = (const float*)d_in[1];
  const float* W_head   = (const float*)d_in[2];
  const float* W_tail   = (const float*)d_in[3];
  const float* W_ent    = (const float*)d_in[4];
  const float* W_rel    = (const float*)d_in[5];
  const float* attn_h   = (const float*)d_in[6];
  const float* attn_t   = (const float*)d_in[7];
  const float* attn_r   = (const float*)d_in[8];
  const float* ln_ent_g = (const float*)d_in[9];
  const float* ln_ent_b = (const float*)d_in[10];
  const float* ln_rel_g = (const float*)d_in[11];
  const float* ln_rel_b = (const float*)d_in[12];
  const float* ln_ff_g  = (const float*)d_in[13];
  const float* ln_ff_b  = (const float*)d_in[14];
  const float* W1       = (const float*)d_in[15];
  const float* b1       = (const float*)d_in[16];
  const float* W2       = (const float*)d_in[17];
  const float* b2       = (const float*)d_in[18];
  const int* src        = (const int*)d_in[19];
  const int* rid        = (const int*)d_in[20];
  float* out = (float*)d_out;

  // Workspace layout. h1 (102.4 MB) ALIASES [0, 102.4 MB): all tensors there
  // are dead before gemm1 runs (edge/diff/proj consumers all finished).
  // fB (final feat) lives OUTSIDE the alias region.
  char* w = (char*)d_ws;
  double* er64  = (double*)(w + 0);           // 1.3 KB   (dead after edge)
  double* Wcomb = (double*)(w + 4096);        // 32 KB    (dead after logits)
  double* eh64 = (double*)(w + 36864);        // 3.2 MB   (dead after edge)
  double* et64 = (double*)(w + 3236864);      // 3.2 MB
  u16*    xb   = (u16*)  (w + 6436864);       // 25.6 MB  (dead after proj)
  u16*    fe   = (u16*)  (w + 32036864);      // 25.6 MB  (dead after hops)
  u16*    fA   = (u16*)  (w + 57636864);      // 25.6 MB  (dead after hops)
  int*    idx6 = (int*)  (w + 83236864);      // 9.6 MB   (dead after hops)
  float*  w6   = (float*)(w + 92836864);      // 9.6 MB   (dead after hops)
  u16*    h1   = (u16*)  (w + 0);             // 102.4 MB alias, gemm1->gemm2
  u16*    fB   = (u16*)  (w + 102436864);     // 25.6 MB  (final feat, live to end)
  u16*    y    = (u16*)  (w + 128036864);     // 25.6 MB
  u16*    Wet  = (u16*)  (w + 153636864);     // 128 KB
  u16*    W1t  = (u16*)  (w + 153767936);     // 512 KB
  u16*    W2t  = (u16*)  (w + 154292224);     // 512 KB  (end 154,816,512)

  castw_kernel<<<2304, 256, 0, stream>>>(W_ent, W1, W2, Wet, W1t, W2t);
  prep_kernel<<<RR+1, 256, 0, stream>>>(rel, W_head, W_tail, W_rel,
                                        attn_h, attn_t, attn_r,
                                        ln_rel_g, ln_rel_b, Wcomb, er64);
  logits_kernel<<<NN/16, 256, 0, stream>>>(ent, ln_ent_g, ln_ent_b, Wcomb,
                                           xb, eh64, et64);
  // proj: fe = xb @ Wet
  {
    dim3 g((NN + 127)/128, 2);
    gemm_kernel<0><<<g, 256, 0, stream>>>(xb, Wet, nullptr, nullptr, nullptr,
                                          fe, nullptr, NN, 256, 256);
  }
  edge_kernel<<<(NN*HH + 255)/256, 256, 0, stream>>>(src, rid, eh64, et64, er64,
                                                     idx6, w6);
  // 10 hops, one dispatch each: 50000 blocks => latency hiding via TLP.
  const u16* cur = fe;
  u16* bufs[2] = { fA, fB };
  for (int hop = 0; hop < HOPN; hop++) {
    u16* nxt = bufs[hop & 1];
    diff_kernel<<<NN, 256, 0, stream>>>(cur, fe, idx6, w6, nxt);
    cur = nxt;                                 // final cur == fB (10 hops)
  }
  ln_ff_kernel<<<NN/4, 256, 0, stream>>>(cur, ent, ln_ff_g, ln_ff_b, y);
  {
    dim3 g((NN + 127)/128, 8);                 // h1 = relu(y@W1 + b1)
    gemm_kernel<1><<<g, 256, 0, stream>>>(y, W1t, b1, nullptr, nullptr,
                                          h1, nullptr, NN, 1024, 256);
  }
  {
    dim3 g((NN + 127)/128, 2);                 // out = h1@W2 + b2 + feat + ent
    gemm_kernel<2><<<g, 256, 0, stream>>>(h1, W2t, b2, cur, ent,
                                          nullptr, out, NN, 256, 1024);
  }
}

// Round 4
// 776.627 us; speedup vs baseline: 1.0433x; 1.0433x over previous
//
#include <hip/hip_runtime.h>

// Problem constants (fixed by reference)
#define NN   50000
#define DD   16
#define FFE  256
#define HH   8
#define DHH  32
#define RR   20
#define HOPN 10

typedef unsigned short u16;
typedef unsigned int   u32;
typedef __attribute__((ext_vector_type(8))) short  short8;   // 8 bf16 = 4 VGPRs
typedef __attribute__((ext_vector_type(4))) float  floatx4;
typedef __attribute__((ext_vector_type(4))) double doublex4; // f64 MFMA acc

__device__ __forceinline__ float b2f(u16 u){ return __uint_as_float(((u32)u)<<16); }
__device__ __forceinline__ u16 f2b(float f){
  u32 x = __float_as_uint(f);
  u32 r = (x + 0x7fffu + ((x>>16)&1u)) >> 16;   // RNE
  return (u16)r;
}

// Async global->LDS DMA, 16B per lane. Dest must be wave-uniform base
// (HW adds lane*16); source is per-lane.
__device__ __forceinline__ void glds16(const u16* g, u16* l) {
  __builtin_amdgcn_global_load_lds(
      (const __attribute__((address_space(1))) void*)g,
      (__attribute__((address_space(3))) void*)l, 16, 0, 0);
}

// ---------------------------------------------------------------------------
// castw: one-off cast+transpose of value-path weights to bf16 [N][K] layout.
// ---------------------------------------------------------------------------
__global__ __launch_bounds__(256) void castw_kernel(
    const float* __restrict__ We, const float* __restrict__ W1,
    const float* __restrict__ W2,
    u16* __restrict__ Wet, u16* __restrict__ W1t, u16* __restrict__ W2t)
{
  int tid = blockIdx.x*256 + threadIdx.x;
  if (tid < 256*256) {                       // W_ent [256][256] -> Wet[n][k]
    int k = tid >> 8, n = tid & 255;
    Wet[n*256 + k] = f2b(We[tid]);
  } else if (tid < 256*256 + 256*1024) {     // W1 [256][1024] -> W1t[n][k]
    int s = tid - 65536;
    int k = s >> 10, n = s & 1023;
    W1t[n*256 + k] = f2b(W1[s]);
  } else if (tid < 589824) {                 // W2 [1024][256] -> W2t[n][k]
    int s = tid - 327680;
    int k = s >> 8, n = s & 255;
    W2t[n*1024 + k] = f2b(W2[s]);
  }
}

// ---------------------------------------------------------------------------
// prep: blocks 0..19 -> LN(rel_feat[r]) @ W_rel -> er[r,h]  (fp64, selection)
//       block 20     -> fold attn into Wcomb[256][16]: cols 0..7 = head,
//                       cols 8..15 = tail (mfma_f64_16x16x4 B layout).
// ---------------------------------------------------------------------------
__global__ __launch_bounds__(256) void prep_kernel(
    const float* __restrict__ rel_feat,
    const float* __restrict__ W_head, const float* __restrict__ W_tail,
    const float* __restrict__ W_rel,
    const float* __restrict__ attn_h, const float* __restrict__ attn_t,
    const float* __restrict__ attn_r,
    const float* __restrict__ lng, const float* __restrict__ lnb,
    double* __restrict__ Wcomb, double* __restrict__ er)
{
  int t = threadIdx.x;
  if (blockIdx.x == RR) {
    for (int h = 0; h < HH; h++) {
      double sh = 0.0, st = 0.0;
      #pragma unroll
      for (int c = 0; c < DHH; c++) {
        int j = h*DHH + c;
        sh += (double)W_head[t*FFE + j] * (double)attn_h[j];
        st += (double)W_tail[t*FFE + j] * (double)attn_t[j];
      }
      Wcomb[t*16 + h]     = sh;   // k = t, n = h      (head side)
      Wcomb[t*16 + 8 + h] = st;   // k = t, n = 8 + h  (tail side)
    }
    return;
  }
  int r = blockIdx.x;
  __shared__ double red[8];
  __shared__ double rln[256];
  double v = (double)rel_feat[r*FFE + t];
  double s = v, q = v*v;
  #pragma unroll
  for (int o = 32; o; o >>= 1) { s += __shfl_xor(s, o, 64); q += __shfl_xor(q, o, 64); }
  if ((t & 63) == 0) { red[t>>6] = s; red[4 + (t>>6)] = q; }
  __syncthreads();
  double stot = red[0]+red[1]+red[2]+red[3];
  double qtot = red[4]+red[5]+red[6]+red[7];
  double mean = stot * (1.0/256.0);
  double var  = qtot * (1.0/256.0) - mean*mean;
  double rstd = 1.0 / sqrt(var + 1e-5);
  rln[t] = (v - mean) * rstd * (double)lng[t] + (double)lnb[t];
  __syncthreads();
  double acc = 0.0;
  for (int k = 0; k < 256; k++) acc += rln[k] * (double)W_rel[k*FFE + t];
  double p = acc * (double)attn_r[t];
  #pragma unroll
  for (int o = 16; o; o >>= 1) p += __shfl_down(p, o, 32);
  if ((t & 31) == 0) er[r*HH + (t>>5)] = p;
}

// ---------------------------------------------------------------------------
// logits: per 16-node tile. LN(ent) in fp64 -> xb (bf16, value path) and
//         eh/et via mfma_f64_16x16x4 (16x16x256 fp64 GEMM per block,
//         K split across the 4 waves, partials reduced via LDS).
// ---------------------------------------------------------------------------
__global__ __launch_bounds__(256) void logits_kernel(
    const float* __restrict__ ent,
    const float* __restrict__ lng, const float* __restrict__ lnb,
    const double* __restrict__ Wcomb,
    u16* __restrict__ xb, double* __restrict__ eh, double* __restrict__ et)
{
  __shared__ double xs[16][257];      // 32.9 KB; also reused for partials
  int tid = threadIdx.x;
  int i0 = blockIdx.x * 16;
  int wave = tid >> 6, lane = tid & 63;
  for (int m = wave; m < 16; m += 4) {
    int row = i0 + m;
    float4 u = *(const float4*)&ent[row*FFE + lane*4];
    double v0 = u.x, v1 = u.y, v2 = u.z, v3 = u.w;
    double s = v0+v1+v2+v3;
    double q = v0*v0 + v1*v1 + v2*v2 + v3*v3;
    #pragma unroll
    for (int o = 32; o; o >>= 1) { s += __shfl_xor(s, o, 64); q += __shfl_xor(q, o, 64); }
    double mean = s * (1.0/256.0);
    double var  = q * (1.0/256.0) - mean*mean;
    double rstd = 1.0 / sqrt(var + 1e-5);
    float4 ug = *(const float4*)&lng[lane*4];
    float4 ub = *(const float4*)&lnb[lane*4];
    double y0 = (v0-mean)*rstd*(double)ug.x + (double)ub.x;
    double y1 = (v1-mean)*rstd*(double)ug.y + (double)ub.y;
    double y2 = (v2-mean)*rstd*(double)ug.z + (double)ub.z;
    double y3 = (v3-mean)*rstd*(double)ug.w + (double)ub.w;
    int c = lane*4;
    xs[m][c] = y0; xs[m][c+1] = y1; xs[m][c+2] = y2; xs[m][c+3] = y3;
    ushort4 o4;
    o4.x = f2b((float)y0); o4.y = f2b((float)y1);
    o4.z = f2b((float)y2); o4.w = f2b((float)y3);
    *(ushort4*)&xb[row*FFE + c] = o4;
  }
  __syncthreads();
  // phase 2: wave w owns K slice [w*64, w*64+64). mfma_f64_16x16x4:
  //   A[m][k]: lane = 16*(k&3) + m ; B[k][n]: lane = 16*(k&3) + n
  //   D[m][n]: col = lane&15, row = (lane>>4)*4 + reg
  int nl = lane & 15, kg = lane >> 4;
  doublex4 c4 = {0.0, 0.0, 0.0, 0.0};
  #pragma unroll
  for (int kk = 0; kk < 16; kk++) {
    int k = wave*64 + kk*4 + kg;
    double a = xs[nl][k];
    double b = Wcomb[k*16 + nl];
    c4 = __builtin_amdgcn_mfma_f64_16x16x4f64(a, b, c4, 0, 0, 0);
  }
  __syncthreads();                    // all xs reads done -> alias as partials
  double* sp = &xs[0][0];             // part[w][m][n] = sp[w*256 + m*16 + n]
  #pragma unroll
  for (int i = 0; i < 4; i++)
    sp[wave*256 + (kg*4 + i)*16 + nl] = c4[i];
  __syncthreads();
  int m = tid >> 4, n = tid & 15;     // one (row, output) per thread
  double v = sp[tid] + sp[256 + tid] + sp[512 + tid] + sp[768 + tid];
  if (n < 8) eh[(i0+m)*HH + n] = v;
  else       et[(i0+m)*HH + (n-8)] = v;
}

// ---------------------------------------------------------------------------
// gemm: C[M,N] = A[M,K]bf16 @ B[N,K]bf16 (B pre-transposed), MFMA 16x16x32.
// m97 structure (round-2 verified: 89 us, 0 bank conflicts): 128x128 tile,
// BK=64, 4 waves (2x2, 64x64 out each), global_load_lds(16B) staging into
// XOR-swizzled linear LDS (granule ^= row&7 on pre-swizzled global source
// AND ds_read side), single-buffered, 2 barriers/step. Explicit dbuf was
// tried (round 3) and REGRESSED (89->107us): compiler drains vmcnt(0) at
// the barrier anyway and 64KB LDS halves blocks/CU, losing the implicit
// cross-block overlap (m114) that does the real latency hiding.
// EPI 0: bf16 store. EPI 1: relu(v+bias) bf16. EPI 2: v+bias+feat+ent fp32.
// ---------------------------------------------------------------------------
template<int EPI>
__global__ __launch_bounds__(256) void gemm_kernel(
    const u16* __restrict__ A, const u16* __restrict__ B,
    const float* __restrict__ bias,
    const u16* __restrict__ feat, const float* __restrict__ ent,
    u16* __restrict__ Obf, float* __restrict__ Of,
    int M, int N, int K)
{
  __shared__ u16 As[128*64];    // [row][k] 16 KB, swizzled storage
  __shared__ u16 Bs[128*64];
  int t = threadIdx.x;
  int i0 = blockIdx.x * 128;
  int n0 = blockIdx.y * 128;
  int w = t >> 6, l = t & 63;
  int wr = w >> 1, wc = w & 1;            // wave -> 64x64 quadrant

  // Staging: wave w stages tile rows [w*32, w*32+32) in 4 chunks of 8 rows.
  // Chunk j: LDS base (w*4+j)*512 u16 (wave-uniform). Lane l covers
  // row = w*32 + j*8 + (l>>3), swizzled source col ((l&7)^(l>>3))*8.
  int lrow = l >> 3;
  int scol = ((l & 7) ^ lrow) * 8;        // pre-swizzled global k-offset (u16)

  // Fragment reads: row = q*64 + f*16 + ln; row&7 == ln&7.
  // u16 col = (ks*32 + (l>>4)*8) ^ ((ln&7)<<3).
  int ln = l & 15, q = l >> 4;
  int colk0 = (q*8) ^ ((ln & 7) << 3);
  int colk1 = colk0 ^ 32;

  floatx4 acc[4][4];
  #pragma unroll
  for (int mt = 0; mt < 4; mt++)
    #pragma unroll
    for (int nt = 0; nt < 4; nt++) acc[mt][nt] = (floatx4){0.f,0.f,0.f,0.f};

  for (int k0 = 0; k0 < K; k0 += 64) {
    #pragma unroll
    for (int j = 0; j < 4; j++) {
      int ra = w*32 + j*8 + lrow;         // tile row this lane sources
      int ga = min(i0 + ra, M-1);         // clamp M boundary (stores predicated)
      glds16(&A[(size_t)ga*K + k0 + scol], &As[(w*4+j)*512]);
      int gb = n0 + ra;                   // N is always a multiple of 128
      glds16(&B[(size_t)gb*K + k0 + scol], &Bs[(w*4+j)*512]);
    }
    __syncthreads();                      // drains vmcnt -> tiles ready
    #pragma unroll
    for (int ks = 0; ks < 2; ks++) {
      int ck = ks ? colk1 : colk0;
      short8 bfr[4], afr[4];
      #pragma unroll
      for (int nt = 0; nt < 4; nt++)
        bfr[nt] = *(const short8*)&Bs[(wc*64 + nt*16 + ln)*64 + ck];
      #pragma unroll
      for (int mt = 0; mt < 4; mt++)
        afr[mt] = *(const short8*)&As[(wr*64 + mt*16 + ln)*64 + ck];
      #pragma unroll
      for (int mt = 0; mt < 4; mt++)
        #pragma unroll
        for (int nt = 0; nt < 4; nt++)
          acc[mt][nt] = __builtin_amdgcn_mfma_f32_16x16x32_bf16(afr[mt], bfr[nt], acc[mt][nt], 0, 0, 0);
    }
    __syncthreads();                      // reads done before next overwrite
  }

  int lr = q * 4;               // C/D layout: col=lane&15, row=(lane>>4)*4+reg
  #pragma unroll
  for (int mt = 0; mt < 4; mt++) {
    #pragma unroll
    for (int nt = 0; nt < 4; nt++) {
      int col = n0 + wc*64 + nt*16 + ln;
      #pragma unroll
      for (int r = 0; r < 4; r++) {
        int row = i0 + wr*64 + mt*16 + lr + r;
        if (row < M) {
          float v = acc[mt][nt][r];
          if (EPI == 0) {
            Obf[(size_t)row*N + col] = f2b(v);
          } else if (EPI == 1) {
            v += bias[col];
            Obf[(size_t)row*N + col] = f2b(v > 0.f ? v : 0.f);
          } else {
            v += bias[col] + b2f(feat[(size_t)row*FFE + col]) + ent[(size_t)row*FFE + col];
            Of[(size_t)row*N + col] = v;
          }
        }
      }
    }
  }
}

// ---------------------------------------------------------------------------
// edge: per (i,h): e_d = leaky(eh[src]+et+er[rid]) in fp64; top-5 (+1 tie slot);
//       weights = exp(e-max)/sum_top5, prescaled by (1-ALPHA)=0.9.
// ---------------------------------------------------------------------------
__global__ __launch_bounds__(256) void edge_kernel(
    const int* __restrict__ src, const int* __restrict__ rid,
    const double* __restrict__ eh, const double* __restrict__ et,
    const double* __restrict__ er,
    int* __restrict__ idx6, float* __restrict__ w6)
{
  int tid = blockIdx.x*256 + threadIdx.x;
  if (tid >= NN*HH) return;
  int i = tid >> 3, h = tid & 7;
  double bet = et[tid];
  double e[16]; int sj[16];
  #pragma unroll
  for (int d = 0; d < 16; d++) {
    int s = src[i*DD + d];
    int rv = rid[i*DD + d];
    sj[d] = s;
    double v = eh[s*HH + h] + bet + er[rv*HH + h];
    e[d] = (v > 0.0) ? v : 0.2 * v;
  }
  u32 mask = 0; double vs[5]; int js[5];
  #pragma unroll
  for (int k = 0; k < 5; k++) {
    double best = -1e300; int bj = 0, bd = 0;
    #pragma unroll
    for (int d = 0; d < 16; d++) {
      bool c = (((mask>>d)&1u) == 0u) && (e[d] > best);
      if (c) { best = e[d]; bj = sj[d]; bd = d; }
    }
    mask |= (1u << bd); vs[k] = best; js[k] = bj;
  }
  double kth = vs[4];
  int j6 = 0; bool f6 = false;
  #pragma unroll
  for (int d = 0; d < 16; d++) {
    if ((((mask>>d)&1u) == 0u) && (e[d] == kth) && !f6) { j6 = sj[d]; f6 = true; }
  }
  float m0 = (float)vs[0];
  float ex[5], ssum = 0.f;
  #pragma unroll
  for (int k = 0; k < 5; k++) { ex[k] = __expf((float)vs[k] - m0); ssum += ex[k]; }
  float inv = 0.9f / ssum;
  long base = (long)tid * 6;
  #pragma unroll
  for (int k = 0; k < 5; k++) { idx6[base+k] = js[k]; w6[base+k] = ex[k]*inv; }
  idx6[base+5] = j6; w6[base+5] = f6 ? ex[4]*inv : 0.f;
}

// ---------------------------------------------------------------------------
// diff: one hop. feat_new = 0.9*sum_k w*feat_old[idx] + 0.1*fe.
// 8 nodes per block (6250 blocks). Each lane owns 8 contiguous bf16
// channels (short8 = 16 B/lane, G13 sweet spot): 4 lanes per (i,h) group
// form one contiguous 64 B segment per gathered row. Replaces the 2-byte-
// per-lane gathers (8x fewer VMEM instructions per hop). All 5 idx/w pairs
// + gathers issued before the FMA chain -> 5-6 loads in flight per thread.
// FP accumulation order per channel unchanged: fe, k0..k4, tie.
// ---------------------------------------------------------------------------
__global__ __launch_bounds__(256) void diff_kernel(
    const u16* __restrict__ fold, const u16* __restrict__ fe,
    const int* __restrict__ idx6, const float* __restrict__ w6,
    u16* __restrict__ fnew)
{
  int tid = threadIdx.x;
  int nb = tid >> 5;                    // node within block (0..7)
  int v  = tid & 31;                    // lane within node
  int h  = v >> 2;                      // head (0..7)
  int cc = (v & 3) * 8;                 // channel chunk within head {0,8,16,24}
  int i  = blockIdx.x*8 + nb;
  int ch = h*DHH + cc;                  // channel base (0..255, step 8)
  long eb = ((long)i*HH + h) * 6;

  int jj[5]; float wv[5];
  #pragma unroll
  for (int k = 0; k < 5; k++) { jj[k] = idx6[eb + k]; wv[k] = w6[eb + k]; }
  short8 g[5];
  #pragma unroll
  for (int k = 0; k < 5; k++)
    g[k] = *(const short8*)&fold[(size_t)jj[k]*FFE + ch];
  short8 f8 = *(const short8*)&fe[(size_t)i*FFE + ch];

  float acc[8];
  #pragma unroll
  for (int j = 0; j < 8; j++) acc[j] = 0.1f * b2f((u16)f8[j]);
  #pragma unroll
  for (int k = 0; k < 5; k++)
    #pragma unroll
    for (int j = 0; j < 8; j++) acc[j] += wv[k] * b2f((u16)g[k][j]);

  float w5 = w6[eb + 5];
  if (w5 != 0.f) {                      // tie slot: almost never taken
    int j5 = idx6[eb + 5];
    short8 g5 = *(const short8*)&fold[(size_t)j5*FFE + ch];
    #pragma unroll
    for (int j = 0; j < 8; j++) acc[j] += w5 * b2f((u16)g5[j]);
  }

  short8 o8;
  #pragma unroll
  for (int j = 0; j < 8; j++) o8[j] = (short)f2b(acc[j]);
  *(short8*)&fnew[(size_t)i*FFE + ch] = o8;
}

// ---------------------------------------------------------------------------
// ln_ff: y = bf16( LN(feat+ent) ).  One wave per row, lane holds 4 elems.
// ---------------------------------------------------------------------------
__global__ __launch_bounds__(256) void ln_ff_kernel(
    const u16* __restrict__ feat, const float* __restrict__ ent,
    const float* __restrict__ g, const float* __restrict__ b,
    u16* __restrict__ y)
{
  int w = threadIdx.x >> 6, l = threadIdx.x & 63;
  int row = blockIdx.x*4 + w;
  float4 e4 = *(const float4*)&ent[row*FFE + l*4];
  ushort4 fv = *(const ushort4*)&feat[row*FFE + l*4];
  float v0 = b2f(fv.x)+e4.x, v1 = b2f(fv.y)+e4.y;
  float v2 = b2f(fv.z)+e4.z, v3 = b2f(fv.w)+e4.w;
  float s = v0+v1+v2+v3;
  float q = v0*v0 + v1*v1 + v2*v2 + v3*v3;
  #pragma unroll
  for (int o = 32; o; o >>= 1) { s += __shfl_xor(s, o, 64); q += __shfl_xor(q, o, 64); }
  float mean = s * (1.f/256.f);
  float var  = q * (1.f/256.f) - mean*mean;
  float rstd = rsqrtf(var + 1e-5f);
  float4 g4 = *(const float4*)&g[l*4];
  float4 b4 = *(const float4*)&b[l*4];
  ushort4 o4;
  o4.x = f2b((v0-mean)*rstd*g4.x + b4.x);
  o4.y = f2b((v1-mean)*rstd*g4.y + b4.y);
  o4.z = f2b((v2-mean)*rstd*g4.z + b4.z);
  o4.w = f2b((v3-mean)*rstd*g4.w + b4.w);
  *(ushort4*)&y[row*FFE + l*4] = o4;
}

// ---------------------------------------------------------------------------
extern "C" void kernel_launch(void* const* d_in, const int* in_sizes, int n_in,
                              void* d_out, int out_size, void* d_ws, size_t ws_size,
                              hipStream_t stream)
{
  const float* ent      = (const float*)d_in[0];
  const float* rel      = (const float*)d_in[1];
  const float* W_head   = (const float*)d_in[2];
  const float* W_tail   = (const float*)d_in[3];
  const float* W_ent    = (const float*)d_in[4];
  const float* W_rel    = (const float*)d_in[5];
  const float* attn_h   = (const float*)d_in[6];
  const float* attn_t   = (const float*)d_in[7];
  const float* attn_r   = (const float*)d_in[8];
  const float* ln_ent_g = (const float*)d_in[9];
  const float* ln_ent_b = (const float*)d_in[10];
  const float* ln_rel_g = (const float*)d_in[11];
  const float* ln_rel_b = (const float*)d_in[12];
  const float* ln_ff_g  = (const float*)d_in[13];
  const float* ln_ff_b  = (const float*)d_in[14];
  const float* W1       = (const float*)d_in[15];
  const float* b1       = (const float*)d_in[16];
  const float* W2       = (const float*)d_in[17];
  const float* b2       = (const float*)d_in[18];
  const int* src        = (const int*)d_in[19];
  const int* rid        = (const int*)d_in[20];
  float* out = (float*)d_out;

  // Workspace layout. h1 (102.4 MB) ALIASES [0, 102.4 MB): all tensors there
  // are dead before gemm1 runs (edge/diff/proj consumers all finished).
  // fB (final feat) lives OUTSIDE the alias region.
  char* w = (char*)d_ws;
  double* er64  = (double*)(w + 0);           // 1.3 KB   (dead after edge)
  double* Wcomb = (double*)(w + 4096);        // 32 KB    (dead after logits)
  double* eh64 = (double*)(w + 36864);        // 3.2 MB   (dead after edge)
  double* et64 = (double*)(w + 3236864);      // 3.2 MB
  u16*    xb   = (u16*)  (w + 6436864);       // 25.6 MB  (dead after proj)
  u16*    fe   = (u16*)  (w + 32036864);      // 25.6 MB  (dead after hops)
  u16*    fA   = (u16*)  (w + 57636864);      // 25.6 MB  (dead after hops)
  int*    idx6 = (int*)  (w + 83236864);      // 9.6 MB   (dead after hops)
  float*  w6   = (float*)(w + 92836864);      // 9.6 MB   (dead after hops)
  u16*    h1   = (u16*)  (w + 0);             // 102.4 MB alias, gemm1->gemm2
  u16*    fB   = (u16*)  (w + 102436864);     // 25.6 MB  (final feat, live to end)
  u16*    y    = (u16*)  (w + 128036864);     // 25.6 MB
  u16*    Wet  = (u16*)  (w + 153636864);     // 128 KB
  u16*    W1t  = (u16*)  (w + 153767936);     // 512 KB
  u16*    W2t  = (u16*)  (w + 154292224);     // 512 KB  (end 154,816,512)

  castw_kernel<<<2304, 256, 0, stream>>>(W_ent, W1, W2, Wet, W1t, W2t);
  prep_kernel<<<RR+1, 256, 0, stream>>>(rel, W_head, W_tail, W_rel,
                                        attn_h, attn_t, attn_r,
                                        ln_rel_g, ln_rel_b, Wcomb, er64);
  logits_kernel<<<NN/16, 256, 0, stream>>>(ent, ln_ent_g, ln_ent_b, Wcomb,
                                           xb, eh64, et64);
  // proj: fe = xb @ Wet
  {
    dim3 g((NN + 127)/128, 2);
    gemm_kernel<0><<<g, 256, 0, stream>>>(xb, Wet, nullptr, nullptr, nullptr,
                                          fe, nullptr, NN, 256, 256);
  }
  edge_kernel<<<(NN*HH + 255)/256, 256, 0, stream>>>(src, rid, eh64, et64, er64,
                                                     idx6, w6);
  // 10 hops, one dispatch each: 6250 blocks x 256 thr, 16B/lane gathers.
  const u16* cur = fe;
  u16* bufs[2] = { fA, fB };
  for (int hop = 0; hop < HOPN; hop++) {
    u16* nxt = bufs[hop & 1];
    diff_kernel<<<NN/8, 256, 0, stream>>>(cur, fe, idx6, w6, nxt);
    cur = nxt;                                 // final cur == fB (10 hops)
  }
  ln_ff_kernel<<<NN/4, 256, 0, stream>>>(cur, ent, ln_ff_g, ln_ff_b, y);
  {
    dim3 g((NN + 127)/128, 8);                 // h1 = relu(y@W1 + b1)
    gemm_kernel<1><<<g, 256, 0, stream>>>(y, W1t, b1, nullptr, nullptr,
                                          h1, nullptr, NN, 1024, 256);
  }
  {
    dim3 g((NN + 127)/128, 2);                 // out = h1@W2 + b2 + feat + ent
    gemm_kernel<2><<<g, 256, 0, stream>>>(h1, W2t, b2, cur, ent,
                                          nullptr, out, NN, 256, 1024);
  }
}